// Round 1
// baseline (10135.455 us; speedup 1.0000x reference)
//
#include <hip/hip_runtime.h>
#include <hip/hip_bf16.h>
#include <math.h>

#define D_  512
#define B_  64
#define T_  50
#define S_  400
#define KT_ 50

typedef unsigned short ushort_t;
typedef __attribute__((ext_vector_type(8))) short bf16x8;
typedef __attribute__((ext_vector_type(4))) float f32x4;

__device__ __forceinline__ float bf2f(ushort_t h){
  union { unsigned u; float f; } v; v.u = ((unsigned)h) << 16; return v.f;
}
__device__ __forceinline__ ushort_t f2bf(float f){
  union { float f; unsigned u; } v; v.f = f;
  unsigned r = (v.u + 0x7fffu + ((v.u >> 16) & 1u)) >> 16;
  return (ushort_t)r;
}
__device__ __forceinline__ float dot4(float4 a, float4 b){
  return a.x*b.x + a.y*b.y + a.z*b.z + a.w*b.w;
}
__device__ __forceinline__ float fast_tanh(float x){
  float e = __expf(2.f*x);
  return 1.f - __fdividef(2.f, e + 1.f);
}
__device__ __forceinline__ float sigmoidf_(float x){
  return __fdividef(1.f, 1.f + __expf(-x));
}

// ---------------------------------------------------------------- convert
__global__ void f32_to_bf16_kernel(const float* __restrict__ in, ushort_t* __restrict__ out, int n){
  int i = blockIdx.x*256 + threadIdx.x;
  if(i < n) out[i] = f2bf(in[i]);
}

// ---------------------------------------------------------------- precompute GEMM
// C_bf16[M][512] = A_bf16[M][512] @ W_bf16[512][512]^T + bias   (rows = (l*64+b))
// grid = M/64, block = 256 (4 waves; wave w owns rows blk*64+16w..+15, all 512 cols)
__global__ void pre_gemm_kernel(const ushort_t* __restrict__ A, const ushort_t* __restrict__ W,
                                const float* __restrict__ bias, ushort_t* __restrict__ C){
  int wave = threadIdx.x >> 6;
  int lane = threadIdx.x & 63;
  int row0 = blockIdx.x*64 + wave*16;
  int arow = row0 + (lane & 15);
  int kgrp = (lane >> 4) * 8;
  f32x4 acc[32];
#pragma unroll
  for(int i=0;i<32;i++) acc[i] = (f32x4){0.f,0.f,0.f,0.f};
  for(int kb=0; kb<16; kb++){
    int k = kb*32 + kgrp;
    bf16x8 a = *(const bf16x8*)(A + (size_t)arow*512 + k);
#pragma unroll
    for(int nt=0; nt<32; nt++){
      bf16x8 b = *(const bf16x8*)(W + (size_t)(nt*16 + (lane&15))*512 + k);
      acc[nt] = __builtin_amdgcn_mfma_f32_16x16x32_bf16(a, b, acc[nt], 0,0,0);
    }
  }
  int crow = row0 + (lane>>4)*4;
  int ccol = lane & 15;
#pragma unroll
  for(int nt=0; nt<32; nt++){
#pragma unroll
    for(int r=0; r<4; r++){
      int col = nt*16 + ccol;
      C[(size_t)(crow+r)*512 + col] = f2bf(acc[nt][r] + bias[col]);
    }
  }
}

// ---------------------------------------------------------------- GRU0 (+fused readout of prev step)
// grid 384, block 128. blocks [0,256): GRU0 (j = blk*2 + tid>>6, b = tid&63)
// blocks [256,384): readout of step t-1 (u = (blk-256)*2 + tid>>6)
__global__ void gru0_readout_kernel(
    const int* __restrict__ tgt_t, const float* __restrict__ emb, const float* __restrict__ mix_gru,
    const float* __restrict__ hprev, float* __restrict__ hnew, float* __restrict__ hdup,
    const float* __restrict__ Wih, const float* __restrict__ Whh,
    const float* __restrict__ bih, const float* __restrict__ bhh,
    int do_gru, int do_readout,
    const int* __restrict__ tgt_prev, const float* __restrict__ h1_prev, const float* __restrict__ mix_prev,
    const float* __restrict__ Wr, const float* __restrict__ br, float* __restrict__ gout)
{
  int blk = blockIdx.x, tid = threadIdx.x;
  int b = tid & 63;
  if(blk < 256){
    if(!do_gru) return;
    int j = blk*2 + (tid>>6);
    const float* xe = emb + (size_t)tgt_t[b]*D_;
    const float* xm = mix_gru + (size_t)b*D_;
    const float* hb = hprev  + (size_t)b*D_;
    const float* wr = Wih + (size_t)j*1024;
    const float* wz = Wih + (size_t)(512+j)*1024;
    const float* wn = Wih + (size_t)(1024+j)*1024;
    float ar=0.f, az=0.f, an=0.f;
    for(int k=0;k<512;k+=4){
      float4 x = *(const float4*)(xe+k);
      ar += dot4(x, *(const float4*)(wr+k));
      az += dot4(x, *(const float4*)(wz+k));
      an += dot4(x, *(const float4*)(wn+k));
    }
    for(int k=0;k<512;k+=4){
      float4 x = *(const float4*)(xm+k);
      ar += dot4(x, *(const float4*)(wr+512+k));
      az += dot4(x, *(const float4*)(wz+512+k));
      an += dot4(x, *(const float4*)(wn+512+k));
    }
    const float* vr = Whh + (size_t)j*512;
    const float* vz = Whh + (size_t)(512+j)*512;
    const float* vn = Whh + (size_t)(1024+j)*512;
    float hr=0.f, hz=0.f, hn=0.f;
    for(int k=0;k<512;k+=4){
      float4 h = *(const float4*)(hb+k);
      hr += dot4(h, *(const float4*)(vr+k));
      hz += dot4(h, *(const float4*)(vz+k));
      hn += dot4(h, *(const float4*)(vn+k));
    }
    float r = sigmoidf_(ar + bih[j]      + hr + bhh[j]);
    float z = sigmoidf_(az + bih[512+j]  + hz + bhh[512+j]);
    float n = fast_tanh(an + bih[1024+j] + r*(hn + bhh[1024+j]));
    float h = (1.f - z)*n + z*hb[j];
    hnew[(size_t)b*D_+j] = h;
    hdup[(size_t)b*D_+j] = h;
  } else {
    if(!do_readout) return;
    int u = (blk-256)*2 + (tid>>6);
    const float* xe = emb + (size_t)tgt_prev[b]*D_;
    const float* xh = h1_prev + (size_t)b*D_;
    const float* xm = mix_prev + (size_t)b*D_;
    const float* wa = Wr + (size_t)(2*u)  *1536;
    const float* wb = Wr + (size_t)(2*u+1)*1536;
    float r0 = br[2*u], r1 = br[2*u+1];
    for(int k=0;k<512;k+=4){
      float4 x = *(const float4*)(xe+k);
      r0 += dot4(x, *(const float4*)(wa+k));
      r1 += dot4(x, *(const float4*)(wb+k));
    }
    for(int k=0;k<512;k+=4){
      float4 x = *(const float4*)(xh+k);
      r0 += dot4(x, *(const float4*)(wa+512+k));
      r1 += dot4(x, *(const float4*)(wb+512+k));
    }
    for(int k=0;k<512;k+=4){
      float4 x = *(const float4*)(xm+k);
      r0 += dot4(x, *(const float4*)(wa+1024+k));
      r1 += dot4(x, *(const float4*)(wb+1024+k));
    }
    gout[(size_t)b*256 + u] = fmaxf(r0, r1);
  }
}

// ---------------------------------------------------------------- GRU1
__global__ void gru1_kernel(const float* __restrict__ xin, const float* __restrict__ hprev,
    float* __restrict__ hnew, float* __restrict__ hdup,
    const float* __restrict__ Wih, const float* __restrict__ Whh,
    const float* __restrict__ bih, const float* __restrict__ bhh)
{
  int b = threadIdx.x & 63;
  int j = blockIdx.x*2 + (threadIdx.x>>6);
  const float* xb = xin  + (size_t)b*D_;
  const float* hb = hprev+ (size_t)b*D_;
  const float* wr = Wih + (size_t)j*512;
  const float* wz = Wih + (size_t)(512+j)*512;
  const float* wn = Wih + (size_t)(1024+j)*512;
  float ar=0.f, az=0.f, an=0.f;
  for(int k=0;k<512;k+=4){
    float4 x = *(const float4*)(xb+k);
    ar += dot4(x, *(const float4*)(wr+k));
    az += dot4(x, *(const float4*)(wz+k));
    an += dot4(x, *(const float4*)(wn+k));
  }
  const float* vr = Whh + (size_t)j*512;
  const float* vz = Whh + (size_t)(512+j)*512;
  const float* vn = Whh + (size_t)(1024+j)*512;
  float hr=0.f, hz=0.f, hn=0.f;
  for(int k=0;k<512;k+=4){
    float4 h = *(const float4*)(hb+k);
    hr += dot4(h, *(const float4*)(vr+k));
    hz += dot4(h, *(const float4*)(vz+k));
    hn += dot4(h, *(const float4*)(vn+k));
  }
  float r = sigmoidf_(ar + bih[j]      + hr + bhh[j]);
  float z = sigmoidf_(az + bih[512+j]  + hz + bhh[512+j]);
  float n = fast_tanh(an + bih[1024+j] + r*(hn + bhh[1024+j]));
  float h = (1.f - z)*n + z*hb[j];
  hnew[(size_t)b*D_+j] = h;
  hdup[(size_t)b*D_+j] = h;
}

// ---------------------------------------------------------------- q / tq projections
// grid 512 x 128: blocks [0,256): q, [256,512): tq
__global__ void qproj_kernel(const float* __restrict__ h1, const float* __restrict__ qW,
                             float* __restrict__ q, const float* __restrict__ tqW, float* __restrict__ tq)
{
  int which = blockIdx.x >> 8;
  int jb = blockIdx.x & 255;
  int b = threadIdx.x & 63;
  int j = jb*2 + (threadIdx.x>>6);
  const float* W = which ? tqW : qW;
  float* out = which ? tq : q;
  const float* hb = h1 + (size_t)b*D_;
  const float* wj = W + (size_t)j*D_;
  float acc = 0.f;
  for(int k=0;k<512;k+=4) acc += dot4(*(const float4*)(hb+k), *(const float4*)(wj+k));
  out[(size_t)b*D_+j] = acc;
}

// ---------------------------------------------------------------- energies + chunk-local softmax partials + partial c
// grid 320, block 256. blocks [0,256): src attn, b=blk>>2 chunk=blk&3 (100 l each)
//                      blocks [256,320): topic attn, b=blk-256 (all 50 l)
// partial layout per slot: [m, s, c[512]]  (514 floats)
__global__ void energy_partial_kernel(
    const ushort_t* __restrict__ preS, const ushort_t* __restrict__ preT,
    const ushort_t* __restrict__ ctxS, const ushort_t* __restrict__ ctxT,
    const float* __restrict__ q, const float* __restrict__ tq,
    const float* __restrict__ vS, const float* __restrict__ vT,
    const float* __restrict__ maskS, const float* __restrict__ maskT,
    float* __restrict__ eS, float* __restrict__ eT,
    float* __restrict__ partS, float* __restrict__ partT)
{
  int blk = blockIdx.x, tid = threadIdx.x;
  int topic = (blk >= 256);
  int b, lbase, L;
  const ushort_t *pre, *ctx; const float *qv, *vv, *mask; float *eout, *part;
  if(!topic){
    b = blk >> 2; int chunk = blk & 3; lbase = chunk*100; L = 100;
    pre = preS; ctx = ctxS; qv = q + (size_t)b*D_; vv = vS; mask = maskS + (size_t)b*S_;
    eout = eS + (size_t)b*S_;
    part = partS + (size_t)(b*4 + chunk)*514;
  } else {
    b = blk - 256; lbase = 0; L = KT_;
    pre = preT; ctx = ctxT; qv = tq + (size_t)b*D_; vv = vT; mask = maskT + (size_t)b*KT_;
    eout = eT + (size_t)b*KT_;
    part = partT + (size_t)b*514;
  }
  __shared__ float sh_e[100];
  __shared__ float red[256];
  int wave = tid >> 6, lane = tid & 63;
  // per-lane q, v slices (8 elems each), invariant over l
  float q8[8], v8[8];
  {
    float4 a = *(const float4*)(qv + lane*8);
    float4 c = *(const float4*)(qv + lane*8 + 4);
    q8[0]=a.x;q8[1]=a.y;q8[2]=a.z;q8[3]=a.w;q8[4]=c.x;q8[5]=c.y;q8[6]=c.z;q8[7]=c.w;
    float4 d = *(const float4*)(vv + lane*8);
    float4 e = *(const float4*)(vv + lane*8 + 4);
    v8[0]=d.x;v8[1]=d.y;v8[2]=d.z;v8[3]=d.w;v8[4]=e.x;v8[5]=e.y;v8[6]=e.z;v8[7]=e.w;
  }
  for(int li = wave; li < L; li += 4){
    int l = lbase + li;
    const ushort_t* pp = pre + ((size_t)l*B_ + b)*D_ + lane*8;
    uint4 pk = *(const uint4*)pp;
    unsigned pw[4] = {pk.x, pk.y, pk.z, pk.w};
    float sum = 0.f;
#pragma unroll
    for(int w=0; w<4; w++){
      float p0 = bf2f((ushort_t)(pw[w] & 0xffffu));
      float p1 = bf2f((ushort_t)(pw[w] >> 16));
      sum += v8[2*w]   * fast_tanh(p0 + q8[2*w]);
      sum += v8[2*w+1] * fast_tanh(p1 + q8[2*w+1]);
    }
#pragma unroll
    for(int off=32; off>=1; off>>=1) sum += __shfl_xor(sum, off);
    if(lane == 0){
      float e = (mask[l] > 0.5f) ? -1e6f : sum;
      sh_e[li] = e; eout[l] = e;      // raw e to d_out; normalized later
    }
  }
  __syncthreads();
  float lm = -3.4e38f;
  for(int i=tid; i<L; i+=256) lm = fmaxf(lm, sh_e[i]);
  red[tid] = lm; __syncthreads();
  for(int s=128; s>0; s>>=1){ if(tid<s) red[tid] = fmaxf(red[tid], red[tid+s]); __syncthreads(); }
  float m = red[0]; __syncthreads();
  for(int i=tid; i<L; i+=256) sh_e[i] = __expf(sh_e[i] - m);
  __syncthreads();
  float ls = 0.f;
  for(int i=tid; i<L; i+=256) ls += sh_e[i];
  red[tid] = ls; __syncthreads();
  for(int s=128; s>0; s>>=1){ if(tid<s) red[tid] += red[tid+s]; __syncthreads(); }
  float ssum = red[0];
  // partial weighted context sum: thread owns d = 2*tid, 2*tid+1
  float c0=0.f, c1=0.f;
  for(int li=0; li<L; li++){
    unsigned u = *(const unsigned*)(ctx + ((size_t)(lbase+li)*B_ + b)*D_ + 2*tid);
    float w = sh_e[li];
    c0 += w * bf2f((ushort_t)(u & 0xffffu));
    c1 += w * bf2f((ushort_t)(u >> 16));
  }
  part[2 + 2*tid] = c0;
  part[3 + 2*tid] = c1;
  if(tid == 0){ part[0] = m; part[1] = ssum; }
}

// ---------------------------------------------------------------- finalize: merge partials, normalize attn,
// gate, mix_new. grid 64 (per b), block 256.
__global__ void finalize_kernel(
    const float* __restrict__ partS, const float* __restrict__ partT,
    float* __restrict__ eS, float* __restrict__ eT,
    const float* __restrict__ h1, const float* __restrict__ gateW, const float* __restrict__ gateb,
    float* __restrict__ mixw, float* __restrict__ mix_out, float* __restrict__ gate_out)
{
  int b = blockIdx.x, tid = threadIdx.x;
  __shared__ float red[256];
  __shared__ float sh[8];   // [0]=M [1]=St [2]=gate [4..7]=chunk factors
  float g = 0.f;
  const float* hb = h1 + (size_t)b*D_;
  for(int k=tid; k<D_; k+=256) g += hb[k]*gateW[k];
  red[tid]=g; __syncthreads();
  for(int s=128;s>0;s>>=1){ if(tid<s) red[tid]+=red[tid+s]; __syncthreads(); }
  if(tid==0){
    sh[2] = sigmoidf_(red[0] + gateb[0]);
    const float* p = partS + (size_t)b*4*514;
    float M = fmaxf(fmaxf(p[0], p[514]), fmaxf(p[2*514], p[3*514]));
    float St = 0.f;
    for(int i=0;i<4;i++){ float f = __expf(p[i*514]-M); sh[4+i]=f; St += p[i*514+1]*f; }
    sh[0]=M; sh[1]=St;
  }
  __syncthreads();
  float M = sh[0], gate = sh[2];
  float rSt = __fdividef(1.f, sh[1]);
  float* er = eS + (size_t)b*S_;
  for(int l=tid; l<S_; l+=256) er[l] = __expf(er[l]-M)*rSt;
  const float* pT = partT + (size_t)b*514;
  float Mt = pT[0];
  float rStt = __fdividef(1.f, pT[1]);
  float* etr = eT + (size_t)b*KT_;
  for(int l=tid; l<KT_; l+=256) etr[l] = __expf(etr[l]-Mt)*rStt;
  const float* p = partS + (size_t)b*4*514;
  for(int d=tid; d<D_; d+=256){
    float c = p[2+d]*sh[4] + p[514+2+d]*sh[5] + p[2*514+2+d]*sh[6] + p[3*514+2+d]*sh[7];
    c *= rSt;
    float tc = pT[2+d]*rStt;
    float mx = gate*c + (1.f-gate)*tc;
    mixw[(size_t)b*D_+d] = mx;
    mix_out[(size_t)b*D_+d] = mx;
  }
  if(tid==0) gate_out[b] = gate;
}

// ================================================================ host
extern "C" void kernel_launch(void* const* d_in, const int* in_sizes, int n_in,
                              void* d_out, int out_size, void* d_ws, size_t ws_size,
                              hipStream_t stream){
  const int*   tgt      = (const int*)  d_in[0];
  const float* hidden   = (const float*)d_in[1];
  const float* context  = (const float*)d_in[2];
  const float* smask    = (const float*)d_in[3];
  const float* tctx_in  = (const float*)d_in[4];
  const float* tmask    = (const float*)d_in[5];
  const float* mix_init = (const float*)d_in[6];
  const float* emb      = (const float*)d_in[7];
  const float* Wih0     = (const float*)d_in[8];
  const float* Whh0     = (const float*)d_in[9];
  const float* bih0     = (const float*)d_in[10];
  const float* bhh0     = (const float*)d_in[11];
  const float* Wih1     = (const float*)d_in[12];
  const float* Whh1     = (const float*)d_in[13];
  const float* bih1     = (const float*)d_in[14];
  const float* bhh1     = (const float*)d_in[15];
  const float* preW     = (const float*)d_in[16];
  const float* preB     = (const float*)d_in[17];
  const float* qW       = (const float*)d_in[18];
  const float* vS       = (const float*)d_in[19];
  const float* tpreW    = (const float*)d_in[20];
  const float* tpreB    = (const float*)d_in[21];
  const float* tqW      = (const float*)d_in[22];
  const float* vT       = (const float*)d_in[23];
  const float* Wr       = (const float*)d_in[24];
  const float* br       = (const float*)d_in[25];
  const float* gW       = (const float*)d_in[26];
  const float* gB       = (const float*)d_in[27];

  float* out = (float*)d_out;
  const size_t o0=0, o1=819200, o2=884736, o3=2164736, o4=2324736, o5=2357504;

  unsigned char* p = (unsigned char*)d_ws;
  auto carve = [&](size_t bytes)->void*{
    void* r = (void*)p; p += (bytes + 255) & ~(size_t)255; return r;
  };
  ushort_t* ctxb   = (ushort_t*)carve((size_t)S_*B_*D_*2);
  ushort_t* tctxb  = (ushort_t*)carve((size_t)KT_*B_*D_*2);
  ushort_t* preb   = (ushort_t*)carve((size_t)S_*B_*D_*2);
  ushort_t* tpreb  = (ushort_t*)carve((size_t)KT_*B_*D_*2);
  ushort_t* preWb  = (ushort_t*)carve((size_t)D_*D_*2);
  ushort_t* tpreWb = (ushort_t*)carve((size_t)D_*D_*2);
  float* h0a  = (float*)carve((size_t)B_*D_*4);
  float* h0b2 = (float*)carve((size_t)B_*D_*4);
  float* h1a  = (float*)carve((size_t)B_*D_*4);
  float* h1b2 = (float*)carve((size_t)B_*D_*4);
  float* mixw = (float*)carve((size_t)B_*D_*4);
  float* qws  = (float*)carve((size_t)B_*D_*4);
  float* tqws = (float*)carve((size_t)B_*D_*4);
  float* partS= (float*)carve((size_t)B_*4*514*4);
  float* partT= (float*)carve((size_t)B_*514*4);

  // one-time: convert to bf16, precompute pre/tpre
  {
    int n1 = S_*B_*D_;
    f32_to_bf16_kernel<<<(n1+255)/256,256,0,stream>>>(context, ctxb, n1);
    int n2 = KT_*B_*D_;
    f32_to_bf16_kernel<<<(n2+255)/256,256,0,stream>>>(tctx_in, tctxb, n2);
    int n3 = D_*D_;
    f32_to_bf16_kernel<<<(n3+255)/256,256,0,stream>>>(preW, preWb, n3);
    f32_to_bf16_kernel<<<(n3+255)/256,256,0,stream>>>(tpreW, tpreWb, n3);
    pre_gemm_kernel<<<(S_*B_)/64,256,0,stream>>>(ctxb,  preWb,  preB,  preb);
    pre_gemm_kernel<<<(KT_*B_)/64,256,0,stream>>>(tctxb, tpreWb, tpreB, tpreb);
  }

  float* h0buf[2] = {h0a, h0b2};
  float* h1buf[2] = {h1a, h1b2};

  for(int t=0; t<T_; t++){
    const float* h0p  = t ? h0buf[(t-1)&1] : hidden;
    const float* h1p  = t ? h1buf[(t-1)&1] : hidden + B_*D_;
    const float* mixg = t ? mixw : mix_init;
    int tprev = t ? (t-1) : 0;
    gru0_readout_kernel<<<384,128,0,stream>>>(
        tgt + (size_t)t*B_, emb, mixg, h0p, h0buf[t&1], out + o1,
        Wih0, Whh0, bih0, bhh0,
        1, (t>0)?1:0,
        tgt + (size_t)tprev*B_, t ? h1buf[(t-1)&1] : hidden + B_*D_, mixw,
        Wr, br, out + o0 + (size_t)tprev*B_*256);
    gru1_kernel<<<256,128,0,stream>>>(h0buf[t&1], h1p, h1buf[t&1], out + o1 + B_*D_,
        Wih1, Whh1, bih1, bhh1);
    qproj_kernel<<<512,128,0,stream>>>(h1buf[t&1], qW, qws, tqW, tqws);
    energy_partial_kernel<<<320,256,0,stream>>>(preb, tpreb, ctxb, tctxb, qws, tqws, vS, vT,
        smask, tmask,
        out + o2 + (size_t)t*B_*S_, out + o3 + (size_t)t*B_*KT_, partS, partT);
    finalize_kernel<<<64,256,0,stream>>>(partS, partT,
        out + o2 + (size_t)t*B_*S_, out + o3 + (size_t)t*B_*KT_,
        h1buf[t&1], gW, gB, mixw, out + o4, out + o5 + (size_t)t*B_);
  }
  // readout for the last step (t = T-1)
  gru0_readout_kernel<<<384,128,0,stream>>>(
      tgt, emb, mixw, hidden, h0buf[0], out + o1,
      Wih0, Whh0, bih0, bhh0,
      0, 1,
      tgt + (size_t)(T_-1)*B_, h1buf[(T_-1)&1], mixw,
      Wr, br, out + o0 + (size_t)(T_-1)*B_*256);
}

// Round 2
// 5461.451 us; speedup vs baseline: 1.8558x; 1.8558x over previous
//
#include <hip/hip_runtime.h>
#include <hip/hip_bf16.h>
#include <math.h>

#define D_  512
#define B_  64
#define T_  50
#define S_  400
#define KT_ 50

typedef unsigned short ushort_t;
typedef __attribute__((ext_vector_type(8))) short bf16x8;
typedef __attribute__((ext_vector_type(4))) float f32x4;

__device__ __forceinline__ float bf2f(ushort_t h){
  union { unsigned u; float f; } v; v.u = ((unsigned)h) << 16; return v.f;
}
__device__ __forceinline__ ushort_t f2bf(float f){
  union { float f; unsigned u; } v; v.f = f;
  unsigned r = (v.u + 0x7fffu + ((v.u >> 16) & 1u)) >> 16;
  return (ushort_t)r;
}
__device__ __forceinline__ float fast_tanh(float x){
  float e = __expf(2.f*x);
  return 1.f - __fdividef(2.f, e + 1.f);
}
__device__ __forceinline__ float sigmoidf_(float x){
  return __fdividef(1.f, 1.f + __expf(-x));
}

// ---------------------------------------------------------------- converts / init
__global__ void f32_to_bf16_kernel(const float* __restrict__ in, ushort_t* __restrict__ out, int n){
  int i = blockIdx.x*256 + threadIdx.x;
  if(i < n) out[i] = f2bf(in[i]);
}

// gather emb rows for all (t,b): row i=t*64+b -> emb[tgt[i]]
__global__ void gather_emb_kernel(const int* __restrict__ tgt, const float* __restrict__ emb,
                                  ushort_t* __restrict__ out){
  int row = blockIdx.x;
  const float* src = emb + (size_t)tgt[row]*D_;
  ushort_t* dst = out + (size_t)row*D_;
  for(int k=threadIdx.x; k<D_; k+=256) dst[k] = f2bf(src[k]);
}

__global__ void init_state_kernel(const float* __restrict__ hidden, const float* __restrict__ mix_init,
                                  float* __restrict__ h0f, ushort_t* __restrict__ h0b,
                                  float* __restrict__ h1f, ushort_t* __restrict__ h1b,
                                  ushort_t* __restrict__ mixb){
  int i = blockIdx.x*256 + threadIdx.x;
  if(i < B_*D_){
    float a = hidden[i];        h0f[i]=a; h0b[i]=f2bf(a);
    float b = hidden[B_*D_+i];  h1f[i]=b; h1b[i]=f2bf(b);
    mixb[i] = f2bf(mix_init[i]);
  }
}

// ---------------------------------------------------------------- precompute GEMMs
// C_bf16[M][512] = A[M][512] @ W[512][512]^T + bias (used for pre/tpre)
__global__ void pre_gemm_kernel(const ushort_t* __restrict__ A, const ushort_t* __restrict__ W,
                                const float* __restrict__ bias, ushort_t* __restrict__ C){
  int wave = threadIdx.x >> 6;
  int lane = threadIdx.x & 63;
  int row0 = blockIdx.x*64 + wave*16;
  int cl = lane & 15;
  int kg = (lane >> 4) * 8;
  f32x4 acc[32];
#pragma unroll
  for(int i=0;i<32;i++) acc[i] = (f32x4){0.f,0.f,0.f,0.f};
  const ushort_t* ap = A + (size_t)(row0+cl)*512 + kg;
  for(int kb=0; kb<16; kb++){
    bf16x8 a = *(const bf16x8*)ap; ap += 32;
#pragma unroll
    for(int nt=0; nt<32; nt++){
      const ushort_t* bp = W + (size_t)(nt*16 + cl)*512 + kb*32 + kg;
      acc[nt] = __builtin_amdgcn_mfma_f32_16x16x32_bf16(a, *(const bf16x8*)bp, acc[nt], 0,0,0);
    }
  }
  int crow = row0 + (lane>>4)*4;
#pragma unroll
  for(int nt=0; nt<32; nt++){
#pragma unroll
    for(int r=0; r<4; r++){
      int col = nt*16 + cl;
      C[(size_t)(crow+r)*512 + col] = f2bf(acc[nt][r] + bias[col]);
    }
  }
}

// C_bf16[M][crowlen] chunk = A[M][512] @ W(rows nbase..nbase+511, rowstride wstride, col-offset koff)^T
// grid (M/64, Nchunks)
__global__ void gemm_nb_kernel(const ushort_t* __restrict__ A, const ushort_t* __restrict__ W,
                               ushort_t* __restrict__ C, int wstride, int koff, int crowlen){
  int wave = threadIdx.x >> 6;
  int lane = threadIdx.x & 63;
  int row0 = blockIdx.x*64 + wave*16;
  int nbase = blockIdx.y*512;
  int cl = lane & 15;
  int kg = (lane >> 4) * 8;
  f32x4 acc[32];
#pragma unroll
  for(int i=0;i<32;i++) acc[i] = (f32x4){0.f,0.f,0.f,0.f};
  const ushort_t* ap = A + (size_t)(row0+cl)*512 + kg;
  const ushort_t* bbase = W + (size_t)(nbase+cl)*wstride + koff + kg;
  size_t step16 = (size_t)16*wstride;
  for(int kb=0; kb<16; kb++){
    bf16x8 a = *(const bf16x8*)ap; ap += 32;
    const ushort_t* bp = bbase + kb*32;
#pragma unroll
    for(int nt=0; nt<32; nt++){
      acc[nt] = __builtin_amdgcn_mfma_f32_16x16x32_bf16(a, *(const bf16x8*)bp, acc[nt], 0,0,0);
      bp += step16;
    }
  }
  int crow = row0 + (lane>>4)*4;
#pragma unroll
  for(int nt=0; nt<32; nt++){
#pragma unroll
    for(int r=0; r<4; r++){
      C[(size_t)(crow+r)*crowlen + nbase + nt*16 + cl] = f2bf(acc[nt][r]);
    }
  }
}

// ---------------------------------------------------------------- per-step GRU (+optional fused readout of prev step)
// grid 32 (+8 readout), block 256. GRU block jb owns output cols jb*16..+15 for all 3 gates,
// wave = m-tile (16 batch rows). Elementwise combine fully in-register.
__global__ __launch_bounds__(256) void gru_step_kernel(
    int do_gru, int do_readout,
    const ushort_t* __restrict__ Ag, const ushort_t* __restrict__ Wg, int wg_stride, int wg_koff,
    const ushort_t* __restrict__ Ah, const ushort_t* __restrict__ Wh,
    const ushort_t* __restrict__ E,          // [64][1536] bf16 (emb-part of gi) or null
    const float* __restrict__ bih, const float* __restrict__ bhh,
    const float* __restrict__ hprev, float* __restrict__ hf, ushort_t* __restrict__ hb,
    float* __restrict__ hdup,
    // fused readout (prev step): r = Remb + R1 + mixb@Wr_mix^T + br; maxout -> gout
    const ushort_t* __restrict__ mixb, const ushort_t* __restrict__ Wrb,
    const ushort_t* __restrict__ Remb_t, const float* __restrict__ R1,
    const float* __restrict__ br, float* __restrict__ gout)
{
  int blk = blockIdx.x;
  int wave = threadIdx.x >> 6;
  int lane = threadIdx.x & 63;
  int cl = lane & 15;
  int kg = (lane >> 4) * 8;
  if(blk < 32){
    if(!do_gru) return;
    int j0 = blk*16;
    f32x4 gr={0.f,0.f,0.f,0.f}, gz=gr, gn=gr, hr=gr, hz=gr, hn=gr;
    const ushort_t* ag = Ag + (size_t)(wave*16+cl)*512 + kg;
    const ushort_t* ah = Ah + (size_t)(wave*16+cl)*512 + kg;
    const ushort_t* bg0 = Wg + (size_t)(j0+cl)*wg_stride + wg_koff + kg;
    const ushort_t* bg1 = bg0 + (size_t)512*wg_stride;
    const ushort_t* bg2 = bg1 + (size_t)512*wg_stride;
    const ushort_t* bh0 = Wh + (size_t)(j0+cl)*512 + kg;
    const ushort_t* bh1 = bh0 + 512*512;
    const ushort_t* bh2 = bh1 + 512*512;
    for(int kb=0; kb<16; kb++){
      bf16x8 a1 = *(const bf16x8*)ag; ag += 32;
      bf16x8 a2 = *(const bf16x8*)ah; ah += 32;
      gr = __builtin_amdgcn_mfma_f32_16x16x32_bf16(a1, *(const bf16x8*)bg0, gr, 0,0,0); bg0 += 32;
      gz = __builtin_amdgcn_mfma_f32_16x16x32_bf16(a1, *(const bf16x8*)bg1, gz, 0,0,0); bg1 += 32;
      gn = __builtin_amdgcn_mfma_f32_16x16x32_bf16(a1, *(const bf16x8*)bg2, gn, 0,0,0); bg2 += 32;
      hr = __builtin_amdgcn_mfma_f32_16x16x32_bf16(a2, *(const bf16x8*)bh0, hr, 0,0,0); bh0 += 32;
      hz = __builtin_amdgcn_mfma_f32_16x16x32_bf16(a2, *(const bf16x8*)bh1, hz, 0,0,0); bh1 += 32;
      hn = __builtin_amdgcn_mfma_f32_16x16x32_bf16(a2, *(const bf16x8*)bh2, hn, 0,0,0); bh2 += 32;
    }
    int c = j0 + cl;
#pragma unroll
    for(int r=0; r<4; r++){
      int m = wave*16 + (lane>>4)*4 + r;
      float gir = gr[r] + bih[c];
      float giz = gz[r] + bih[512+c];
      float gin = gn[r] + bih[1024+c];
      if(E){
        const ushort_t* em = E + (size_t)m*1536;
        gir += bf2f(em[c]); giz += bf2f(em[512+c]); gin += bf2f(em[1024+c]);
      }
      float ghr = hr[r] + bhh[c];
      float ghz = hz[r] + bhh[512+c];
      float ghn = hn[r] + bhh[1024+c];
      float rr = sigmoidf_(gir + ghr);
      float zz = sigmoidf_(giz + ghz);
      float nn = fast_tanh(gin + rr*ghn);
      float hp = hprev[(size_t)m*512 + c];
      float h = (1.f - zz)*nn + zz*hp;
      hf  [(size_t)m*512 + c] = h;
      hb  [(size_t)m*512 + c] = f2bf(h);
      hdup[(size_t)m*512 + c] = h;
    }
  } else {
    if(!do_readout) return;
    int n0 = (blk-32)*64;
    f32x4 acc[4];
#pragma unroll
    for(int i=0;i<4;i++) acc[i] = (f32x4){0.f,0.f,0.f,0.f};
    const ushort_t* ap = mixb + (size_t)(wave*16+cl)*512 + kg;
    const ushort_t* bbase = Wrb + (size_t)(n0+cl)*1536 + 1024 + kg;
    for(int kb=0; kb<16; kb++){
      bf16x8 a = *(const bf16x8*)ap; ap += 32;
      const ushort_t* bp = bbase + kb*32;
#pragma unroll
      for(int nt=0; nt<4; nt++){
        acc[nt] = __builtin_amdgcn_mfma_f32_16x16x32_bf16(a, *(const bf16x8*)bp, acc[nt], 0,0,0);
        bp += (size_t)16*1536;
      }
    }
#pragma unroll
    for(int nt=0; nt<4; nt++){
      int c = n0 + nt*16 + cl;
#pragma unroll
      for(int r=0; r<4; r++){
        int m = wave*16 + (lane>>4)*4 + r;
        float v = acc[nt][r] + br[c] + bf2f(Remb_t[(size_t)m*512 + c]) + R1[(size_t)m*512 + c];
        float o = __shfl_xor(v, 1);
        if((cl & 1) == 0) gout[(size_t)m*256 + (c>>1)] = fmaxf(v, o);
      }
    }
  }
}

// ---------------------------------------------------------------- q / tq / readout-out-part from h1
// grid 12: kind = blk>>2 (0=q,1=tq,2=rout), chunk = blk&3 (128 cols). f32 outputs.
__global__ __launch_bounds__(256) void qproj3_kernel(const ushort_t* __restrict__ h1b,
    const ushort_t* __restrict__ qWb, const ushort_t* __restrict__ tqWb, const ushort_t* __restrict__ Wrb,
    float* __restrict__ q, float* __restrict__ tq, float* __restrict__ R1)
{
  int blk = blockIdx.x;
  int kind = blk >> 2, ch = blk & 3;
  int wave = threadIdx.x >> 6, lane = threadIdx.x & 63;
  int cl = lane & 15, kg = (lane>>4)*8;
  const ushort_t* W; int stride, koff; float* out;
  if(kind == 0){ W = qWb;  stride = 512;  koff = 0;   out = q;  }
  else if(kind == 1){ W = tqWb; stride = 512;  koff = 0;   out = tq; }
  else { W = Wrb;  stride = 1536; koff = 512; out = R1; }
  int n0 = ch*128;
  f32x4 acc[8];
#pragma unroll
  for(int i=0;i<8;i++) acc[i] = (f32x4){0.f,0.f,0.f,0.f};
  const ushort_t* ap = h1b + (size_t)(wave*16+cl)*512 + kg;
  const ushort_t* bbase = W + (size_t)(n0+cl)*stride + koff + kg;
  size_t step16 = (size_t)16*stride;
  for(int kb=0; kb<16; kb++){
    bf16x8 a = *(const bf16x8*)ap; ap += 32;
    const ushort_t* bp = bbase + kb*32;
#pragma unroll
    for(int nt=0; nt<8; nt++){
      acc[nt] = __builtin_amdgcn_mfma_f32_16x16x32_bf16(a, *(const bf16x8*)bp, acc[nt], 0,0,0);
      bp += step16;
    }
  }
#pragma unroll
  for(int nt=0; nt<8; nt++){
#pragma unroll
    for(int r=0; r<4; r++){
      int m = wave*16 + (lane>>4)*4 + r;
      out[(size_t)m*512 + n0 + nt*16 + cl] = acc[nt][r];
    }
  }
}

// ---------------------------------------------------------------- energies + chunk softmax partials + partial c
__global__ void energy_partial_kernel(
    const ushort_t* __restrict__ preS, const ushort_t* __restrict__ preT,
    const ushort_t* __restrict__ ctxS, const ushort_t* __restrict__ ctxT,
    const float* __restrict__ q, const float* __restrict__ tq,
    const float* __restrict__ vS, const float* __restrict__ vT,
    const float* __restrict__ maskS, const float* __restrict__ maskT,
    float* __restrict__ eS, float* __restrict__ eT,
    float* __restrict__ partS, float* __restrict__ partT)
{
  int blk = blockIdx.x, tid = threadIdx.x;
  int topic = (blk >= 256);
  int b, lbase, L;
  const ushort_t *pre, *ctx; const float *qv, *vv, *mask; float *eout, *part;
  if(!topic){
    b = blk >> 2; int chunk = blk & 3; lbase = chunk*100; L = 100;
    pre = preS; ctx = ctxS; qv = q + (size_t)b*D_; vv = vS; mask = maskS + (size_t)b*S_;
    eout = eS + (size_t)b*S_;
    part = partS + (size_t)(b*4 + chunk)*514;
  } else {
    b = blk - 256; lbase = 0; L = KT_;
    pre = preT; ctx = ctxT; qv = tq + (size_t)b*D_; vv = vT; mask = maskT + (size_t)b*KT_;
    eout = eT + (size_t)b*KT_;
    part = partT + (size_t)b*514;
  }
  __shared__ float sh_e[100];
  __shared__ float red[256];
  int wave = tid >> 6, lane = tid & 63;
  float q8[8], v8[8];
  {
    float4 a = *(const float4*)(qv + lane*8);
    float4 c = *(const float4*)(qv + lane*8 + 4);
    q8[0]=a.x;q8[1]=a.y;q8[2]=a.z;q8[3]=a.w;q8[4]=c.x;q8[5]=c.y;q8[6]=c.z;q8[7]=c.w;
    float4 d = *(const float4*)(vv + lane*8);
    float4 e = *(const float4*)(vv + lane*8 + 4);
    v8[0]=d.x;v8[1]=d.y;v8[2]=d.z;v8[3]=d.w;v8[4]=e.x;v8[5]=e.y;v8[6]=e.z;v8[7]=e.w;
  }
  for(int li = wave; li < L; li += 4){
    int l = lbase + li;
    const ushort_t* pp = pre + ((size_t)l*B_ + b)*D_ + lane*8;
    uint4 pk = *(const uint4*)pp;
    unsigned pw[4] = {pk.x, pk.y, pk.z, pk.w};
    float sum = 0.f;
#pragma unroll
    for(int w=0; w<4; w++){
      float p0 = bf2f((ushort_t)(pw[w] & 0xffffu));
      float p1 = bf2f((ushort_t)(pw[w] >> 16));
      sum += v8[2*w]   * fast_tanh(p0 + q8[2*w]);
      sum += v8[2*w+1] * fast_tanh(p1 + q8[2*w+1]);
    }
#pragma unroll
    for(int off=32; off>=1; off>>=1) sum += __shfl_xor(sum, off);
    if(lane == 0){
      float e = (mask[l] > 0.5f) ? -1e6f : sum;
      sh_e[li] = e; eout[l] = e;
    }
  }
  __syncthreads();
  float lm = -3.4e38f;
  for(int i=tid; i<L; i+=256) lm = fmaxf(lm, sh_e[i]);
  red[tid] = lm; __syncthreads();
  for(int s=128; s>0; s>>=1){ if(tid<s) red[tid] = fmaxf(red[tid], red[tid+s]); __syncthreads(); }
  float m = red[0]; __syncthreads();
  for(int i=tid; i<L; i+=256) sh_e[i] = __expf(sh_e[i] - m);
  __syncthreads();
  float ls = 0.f;
  for(int i=tid; i<L; i+=256) ls += sh_e[i];
  red[tid] = ls; __syncthreads();
  for(int s=128; s>0; s>>=1){ if(tid<s) red[tid] += red[tid+s]; __syncthreads(); }
  float ssum = red[0];
  float c0=0.f, c1=0.f;
  for(int li=0; li<L; li++){
    unsigned u = *(const unsigned*)(ctx + ((size_t)(lbase+li)*B_ + b)*D_ + 2*tid);
    float w = sh_e[li];
    c0 += w * bf2f((ushort_t)(u & 0xffffu));
    c1 += w * bf2f((ushort_t)(u >> 16));
  }
  part[2 + 2*tid] = c0;
  part[3 + 2*tid] = c1;
  if(tid == 0){ part[0] = m; part[1] = ssum; }
}

// ---------------------------------------------------------------- finalize
__global__ void finalize_kernel(
    const float* __restrict__ partS, const float* __restrict__ partT,
    float* __restrict__ eS, float* __restrict__ eT,
    const float* __restrict__ h1, const float* __restrict__ gateW, const float* __restrict__ gateb,
    ushort_t* __restrict__ mixb, float* __restrict__ mix_out, float* __restrict__ gate_out)
{
  int b = blockIdx.x, tid = threadIdx.x;
  __shared__ float red[256];
  __shared__ float sh[8];
  float g = 0.f;
  const float* hb = h1 + (size_t)b*D_;
  for(int k=tid; k<D_; k+=256) g += hb[k]*gateW[k];
  red[tid]=g; __syncthreads();
  for(int s=128;s>0;s>>=1){ if(tid<s) red[tid]+=red[tid+s]; __syncthreads(); }
  if(tid==0){
    sh[2] = sigmoidf_(red[0] + gateb[0]);
    const float* p = partS + (size_t)b*4*514;
    float M = fmaxf(fmaxf(p[0], p[514]), fmaxf(p[2*514], p[3*514]));
    float St = 0.f;
    for(int i=0;i<4;i++){ float f = __expf(p[i*514]-M); sh[4+i]=f; St += p[i*514+1]*f; }
    sh[0]=M; sh[1]=St;
  }
  __syncthreads();
  float M = sh[0], gate = sh[2];
  float rSt = __fdividef(1.f, sh[1]);
  float* er = eS + (size_t)b*S_;
  for(int l=tid; l<S_; l+=256) er[l] = __expf(er[l]-M)*rSt;
  const float* pT = partT + (size_t)b*514;
  float Mt = pT[0];
  float rStt = __fdividef(1.f, pT[1]);
  float* etr = eT + (size_t)b*KT_;
  for(int l=tid; l<KT_; l+=256) etr[l] = __expf(etr[l]-Mt)*rStt;
  const float* p = partS + (size_t)b*4*514;
  for(int d=tid; d<D_; d+=256){
    float c = p[2+d]*sh[4] + p[514+2+d]*sh[5] + p[2*514+2+d]*sh[6] + p[3*514+2+d]*sh[7];
    c *= rSt;
    float tc = pT[2+d]*rStt;
    float mx = gate*c + (1.f-gate)*tc;
    mixb[(size_t)b*D_+d] = f2bf(mx);
    mix_out[(size_t)b*D_+d] = mx;
  }
  if(tid==0) gate_out[b] = gate;
}

// ================================================================ host
extern "C" void kernel_launch(void* const* d_in, const int* in_sizes, int n_in,
                              void* d_out, int out_size, void* d_ws, size_t ws_size,
                              hipStream_t stream){
  const int*   tgt      = (const int*)  d_in[0];
  const float* hidden   = (const float*)d_in[1];
  const float* context  = (const float*)d_in[2];
  const float* smask    = (const float*)d_in[3];
  const float* tctx_in  = (const float*)d_in[4];
  const float* tmask    = (const float*)d_in[5];
  const float* mix_init = (const float*)d_in[6];
  const float* emb      = (const float*)d_in[7];
  const float* Wih0     = (const float*)d_in[8];
  const float* Whh0     = (const float*)d_in[9];
  const float* bih0     = (const float*)d_in[10];
  const float* bhh0     = (const float*)d_in[11];
  const float* Wih1     = (const float*)d_in[12];
  const float* Whh1     = (const float*)d_in[13];
  const float* bih1     = (const float*)d_in[14];
  const float* bhh1     = (const float*)d_in[15];
  const float* preW     = (const float*)d_in[16];
  const float* preB     = (const float*)d_in[17];
  const float* qW       = (const float*)d_in[18];
  const float* vS       = (const float*)d_in[19];
  const float* tpreW    = (const float*)d_in[20];
  const float* tpreB    = (const float*)d_in[21];
  const float* tqW      = (const float*)d_in[22];
  const float* vT       = (const float*)d_in[23];
  const float* Wr       = (const float*)d_in[24];
  const float* br       = (const float*)d_in[25];
  const float* gW       = (const float*)d_in[26];
  const float* gB       = (const float*)d_in[27];

  float* out = (float*)d_out;
  const size_t o0=0, o1=819200, o2=884736, o3=2164736, o4=2324736, o5=2357504;

  unsigned char* p = (unsigned char*)d_ws;
  auto carve = [&](size_t bytes)->void*{
    void* r = (void*)p; p += (bytes + 255) & ~(size_t)255; return r;
  };
  ushort_t* ctxb   = (ushort_t*)carve((size_t)S_*B_*D_*2);
  ushort_t* tctxb  = (ushort_t*)carve((size_t)KT_*B_*D_*2);
  ushort_t* preb   = (ushort_t*)carve((size_t)S_*B_*D_*2);
  ushort_t* tpreb  = (ushort_t*)carve((size_t)KT_*B_*D_*2);
  ushort_t* preWb  = (ushort_t*)carve((size_t)D_*D_*2);
  ushort_t* tpreWb = (ushort_t*)carve((size_t)D_*D_*2);
  ushort_t* Wih0b  = (ushort_t*)carve((size_t)1536*1024*2);
  ushort_t* Whh0b  = (ushort_t*)carve((size_t)1536*512*2);
  ushort_t* Wih1b  = (ushort_t*)carve((size_t)1536*512*2);
  ushort_t* Whh1b  = (ushort_t*)carve((size_t)1536*512*2);
  ushort_t* qWb    = (ushort_t*)carve((size_t)512*512*2);
  ushort_t* tqWb   = (ushort_t*)carve((size_t)512*512*2);
  ushort_t* Wrb    = (ushort_t*)carve((size_t)512*1536*2);
  ushort_t* Aembb  = (ushort_t*)carve((size_t)T_*B_*D_*2);
  ushort_t* E0     = (ushort_t*)carve((size_t)T_*B_*1536*2);
  ushort_t* Remb   = (ushort_t*)carve((size_t)T_*B_*512*2);
  float* h0f0 = (float*)carve((size_t)B_*D_*4);
  float* h0f1 = (float*)carve((size_t)B_*D_*4);
  float* h1f0 = (float*)carve((size_t)B_*D_*4);
  float* h1f1 = (float*)carve((size_t)B_*D_*4);
  ushort_t* h0b0 = (ushort_t*)carve((size_t)B_*D_*2);
  ushort_t* h0b1 = (ushort_t*)carve((size_t)B_*D_*2);
  ushort_t* h1b0 = (ushort_t*)carve((size_t)B_*D_*2);
  ushort_t* h1b1 = (ushort_t*)carve((size_t)B_*D_*2);
  ushort_t* mixb = (ushort_t*)carve((size_t)B_*D_*2);
  float* qws  = (float*)carve((size_t)B_*D_*4);
  float* tqws = (float*)carve((size_t)B_*D_*4);
  float* R1   = (float*)carve((size_t)B_*D_*4);
  float* partS= (float*)carve((size_t)B_*4*514*4);
  float* partT= (float*)carve((size_t)B_*514*4);

  // -------- one-time precompute --------
  {
    auto cv = [&](const float* src, ushort_t* dst, int n){
      f32_to_bf16_kernel<<<(n+255)/256,256,0,stream>>>(src, dst, n);
    };
    cv(context, ctxb, S_*B_*D_);
    cv(tctx_in, tctxb, KT_*B_*D_);
    cv(preW, preWb, D_*D_);
    cv(tpreW, tpreWb, D_*D_);
    cv(Wih0, Wih0b, 1536*1024);
    cv(Whh0, Whh0b, 1536*512);
    cv(Wih1, Wih1b, 1536*512);
    cv(Whh1, Whh1b, 1536*512);
    cv(qW, qWb, 512*512);
    cv(tqW, tqWb, 512*512);
    cv(Wr, Wrb, 512*1536);
    gather_emb_kernel<<<T_*B_,256,0,stream>>>(tgt, emb, Aembb);
    init_state_kernel<<<(B_*D_+255)/256,256,0,stream>>>(hidden, mix_init, h0f1, h0b1, h1f1, h1b1, mixb);
    pre_gemm_kernel<<<(S_*B_)/64,256,0,stream>>>(ctxb,  preWb,  preB,  preb);
    pre_gemm_kernel<<<(KT_*B_)/64,256,0,stream>>>(tctxb, tpreWb, tpreB, tpreb);
    // E0[t,b,:] = emb_row @ Wih0[:, :512]^T   (bf16)
    gemm_nb_kernel<<<dim3(T_*B_/64,3),256,0,stream>>>(Aembb, Wih0b, E0, 1024, 0, 1536);
    // Remb[t,b,:] = emb_row @ Wr[:, :512]^T   (bf16)
    gemm_nb_kernel<<<dim3(T_*B_/64,1),256,0,stream>>>(Aembb, Wrb, Remb, 1536, 0, 512);
  }

  float* h0f[2] = {h0f0, h0f1};
  float* h1f[2] = {h1f0, h1f1};
  ushort_t* h0b[2] = {h0b0, h0b1};
  ushort_t* h1b[2] = {h1b0, h1b1};

  for(int t=0; t<T_; t++){
    int cur = t & 1, prv = (t+1) & 1;
    // K1: GRU0 (+ fused readout of step t-1)
    gru_step_kernel<<<40,256,0,stream>>>(
        1, (t>0)?1:0,
        mixb, Wih0b, 1024, 512, h0b[prv], Whh0b,
        E0 + (size_t)t*B_*1536, bih0, bhh0,
        h0f[prv], h0f[cur], h0b[cur], out + o1,
        mixb, Wrb, Remb + (size_t)(t>0?t-1:0)*B_*512, R1, br,
        out + o0 + (size_t)(t>0?t-1:0)*B_*256);
    // K2: GRU1
    gru_step_kernel<<<32,256,0,stream>>>(
        1, 0,
        h0b[cur], Wih1b, 512, 0, h1b[prv], Whh1b,
        (const ushort_t*)nullptr, bih1, bhh1,
        h1f[prv], h1f[cur], h1b[cur], out + o1 + B_*D_,
        mixb, Wrb, Remb, R1, br, out + o0);
    // K3: q, tq, readout-out-part
    qproj3_kernel<<<12,256,0,stream>>>(h1b[cur], qWb, tqWb, Wrb, qws, tqws, R1);
    // K4: energies + softmax partials
    energy_partial_kernel<<<320,256,0,stream>>>(preb, tpreb, ctxb, tctxb, qws, tqws, vS, vT,
        smask, tmask,
        out + o2 + (size_t)t*B_*S_, out + o3 + (size_t)t*B_*KT_, partS, partT);
    // K5: finalize (gate, mix, attn normalize)
    finalize_kernel<<<64,256,0,stream>>>(partS, partT,
        out + o2 + (size_t)t*B_*S_, out + o3 + (size_t)t*B_*KT_,
        h1f[cur], gW, gB, mixb, out + o4, out + o5 + (size_t)t*B_);
  }
  // tail: readout for step T-1
  gru_step_kernel<<<40,256,0,stream>>>(
      0, 1,
      mixb, Wih0b, 1024, 512, h0b1, Whh0b,
      (const ushort_t*)nullptr, bih0, bhh0,
      h0f1, h0f0, h0b0, out + o1,
      mixb, Wrb, Remb + (size_t)(T_-1)*B_*512, R1, br,
      out + o0 + (size_t)(T_-1)*B_*256);
}

// Round 3
// 3132.522 us; speedup vs baseline: 3.2356x; 1.7435x over previous
//
#include <hip/hip_runtime.h>
#include <hip/hip_bf16.h>
#include <math.h>

#define D_  512
#define B_  64
#define T_  50
#define S_  400
#define KT_ 50

typedef unsigned short ushort_t;
typedef __attribute__((ext_vector_type(8))) short bf16x8;
typedef __attribute__((ext_vector_type(4))) float f32x4;

__device__ __forceinline__ float bf2f(ushort_t h){
  union { unsigned u; float f; } v; v.u = ((unsigned)h) << 16; return v.f;
}
__device__ __forceinline__ ushort_t f2bf(float f){
  union { float f; unsigned u; } v; v.f = f;
  unsigned r = (v.u + 0x7fffu + ((v.u >> 16) & 1u)) >> 16;
  return (ushort_t)r;
}
__device__ __forceinline__ float fast_tanh(float x){
  float e = __expf(2.f*x);
  return 1.f - __fdividef(2.f, e + 1.f);
}
__device__ __forceinline__ float sigmoidf_(float x){
  return __fdividef(1.f, 1.f + __expf(-x));
}
// fragment-swizzled offset for a [N][512] matrix consumed as MFMA A or B operand.
// lane l of tile (ntile, kb) reads elems [(ntile*16+kb)*512 + l*8 .. +7] and gets
// M/N-row = ntile*16 + (l&15), k = kb*32 + (l>>4)*8 + j  (verified layout, round 2 passed)
__device__ __forceinline__ int swz512(int n, int k){
  return ((n>>4)*16 + (k>>5))*512 + ((n&15) + ((k>>3)&3)*16)*8 + (k&7);
}

// ---------------------------------------------------------------- converts / init
__global__ void f32_to_bf16_kernel(const float* __restrict__ in, ushort_t* __restrict__ out, int n){
  int i = blockIdx.x*256 + threadIdx.x;
  if(i < n) out[i] = f2bf(in[i]);
}

// swizzle a 512x512 f32 slice (row0/col0/stride) into MFMA fragment order (bf16)
__global__ void swizzle_w_kernel(const float* __restrict__ W, ushort_t* __restrict__ out,
                                 int row0, int col0, int stride){
  int i = blockIdx.x*256 + threadIdx.x;
  if(i >= 512*512) return;
  int n = i >> 9, k = i & 511;
  out[swz512(n,k)] = f2bf(W[(size_t)(row0+n)*stride + col0 + k]);
}

__global__ void gather_emb_kernel(const int* __restrict__ tgt, const float* __restrict__ emb,
                                  ushort_t* __restrict__ out){
  int row = blockIdx.x;
  const float* src = emb + (size_t)tgt[row]*D_;
  ushort_t* dst = out + (size_t)row*D_;
  for(int k=threadIdx.x; k<D_; k+=256) dst[k] = f2bf(src[k]);
}

__global__ void init_state_kernel(const float* __restrict__ hidden, const float* __restrict__ mix_init,
                                  float* __restrict__ h0f, ushort_t* __restrict__ h0swz,
                                  float* __restrict__ h1f, ushort_t* __restrict__ h1swz,
                                  ushort_t* __restrict__ mixswz){
  int i = blockIdx.x*256 + threadIdx.x;
  if(i < B_*D_){
    int m = i>>9, k = i&511;
    float a = hidden[i];        h0f[i]=a; h0swz[swz512(m,k)]=f2bf(a);
    float b = hidden[B_*D_+i];  h1f[i]=b; h1swz[swz512(m,k)]=f2bf(b);
    mixswz[swz512(m,k)] = f2bf(mix_init[i]);
  }
}

// ---------------------------------------------------------------- one-time GEMMs (plain layouts)
__global__ void pre_gemm_kernel(const ushort_t* __restrict__ A, const ushort_t* __restrict__ W,
                                const float* __restrict__ bias, ushort_t* __restrict__ C){
  int wave = threadIdx.x >> 6;
  int lane = threadIdx.x & 63;
  int row0 = blockIdx.x*64 + wave*16;
  int cl = lane & 15;
  int kg = (lane >> 4) * 8;
  f32x4 acc[32];
#pragma unroll
  for(int i=0;i<32;i++) acc[i] = (f32x4){0.f,0.f,0.f,0.f};
  const ushort_t* ap = A + (size_t)(row0+cl)*512 + kg;
  for(int kb=0; kb<16; kb++){
    bf16x8 a = *(const bf16x8*)ap; ap += 32;
#pragma unroll
    for(int nt=0; nt<32; nt++){
      const ushort_t* bp = W + (size_t)(nt*16 + cl)*512 + kb*32 + kg;
      acc[nt] = __builtin_amdgcn_mfma_f32_16x16x32_bf16(a, *(const bf16x8*)bp, acc[nt], 0,0,0);
    }
  }
  int crow = row0 + (lane>>4)*4;
#pragma unroll
  for(int nt=0; nt<32; nt++){
#pragma unroll
    for(int r=0; r<4; r++){
      int col = nt*16 + cl;
      C[(size_t)(crow+r)*512 + col] = f2bf(acc[nt][r] + bias[col]);
    }
  }
}

__global__ void gemm_nb_kernel(const ushort_t* __restrict__ A, const ushort_t* __restrict__ W,
                               ushort_t* __restrict__ C, int wstride, int koff, int crowlen){
  int wave = threadIdx.x >> 6;
  int lane = threadIdx.x & 63;
  int row0 = blockIdx.x*64 + wave*16;
  int nbase = blockIdx.y*512;
  int cl = lane & 15;
  int kg = (lane >> 4) * 8;
  f32x4 acc[32];
#pragma unroll
  for(int i=0;i<32;i++) acc[i] = (f32x4){0.f,0.f,0.f,0.f};
  const ushort_t* ap = A + (size_t)(row0+cl)*512 + kg;
  const ushort_t* bbase = W + (size_t)(nbase+cl)*wstride + koff + kg;
  size_t step16 = (size_t)16*wstride;
  for(int kb=0; kb<16; kb++){
    bf16x8 a = *(const bf16x8*)ap; ap += 32;
    const ushort_t* bp = bbase + kb*32;
#pragma unroll
    for(int nt=0; nt<32; nt++){
      acc[nt] = __builtin_amdgcn_mfma_f32_16x16x32_bf16(a, *(const bf16x8*)bp, acc[nt], 0,0,0);
      bp += step16;
    }
  }
  int crow = row0 + (lane>>4)*4;
#pragma unroll
  for(int nt=0; nt<32; nt++){
#pragma unroll
    for(int r=0; r<4; r++){
      C[(size_t)(crow+r)*crowlen + nbase + nt*16 + cl] = f2bf(acc[nt][r]);
    }
  }
}

// ---------------------------------------------------------------- per-step GRU (+fused readout of prev step)
// grid 256 (GRU: 0-127, readout: 128-255), block 384 (6 waves).
// GRU block (mt,nt): wave g<3 -> gi gate g (A=Agi), g>=3 -> gh gate g-3 (A=Agh); LDS combine.
// Readout block (mt,nt): 4 waves K-split over mix @ Wr_mix^T; LDS reduce; +Remb+R1+br; maxout.
__global__ __launch_bounds__(384) void gru_step_kernel(
    int do_gru, int do_readout,
    const ushort_t* __restrict__ Agi, const ushort_t* __restrict__ Agh,
    const ushort_t* __restrict__ Wg, const ushort_t* __restrict__ Wh,
    const ushort_t* __restrict__ E,
    const float* __restrict__ bih, const float* __restrict__ bhh,
    const float* __restrict__ hprevf, float* __restrict__ hf,
    ushort_t* __restrict__ hswz, float* __restrict__ hdup,
    const ushort_t* __restrict__ Amix, const ushort_t* __restrict__ Wrm,
    const ushort_t* __restrict__ Remb_t, const float* __restrict__ R1,
    const float* __restrict__ br, float* __restrict__ gout)
{
  __shared__ float lds[6*256];
  int blk = blockIdx.x;
  int wave = threadIdx.x >> 6, lane = threadIdx.x & 63;
  if(blk < 128){
    if(!do_gru) return;
    int mt = blk >> 5, nt = blk & 31;
    f32x4 acc = (f32x4){0.f,0.f,0.f,0.f};
    const ushort_t* A = (wave < 3) ? Agi : Agh;
    const ushort_t* W = (wave < 3) ? (Wg + wave*262144) : (Wh + (wave-3)*262144);
    const ushort_t* ap = A + (mt*16*512) + lane*8;
    const ushort_t* bp = W + (nt*16*512) + lane*8;
#pragma unroll 4
    for(int kb=0; kb<16; kb++){
      acc = __builtin_amdgcn_mfma_f32_16x16x32_bf16(
          *(const bf16x8*)(ap + kb*512), *(const bf16x8*)(bp + kb*512), acc, 0,0,0);
    }
    *(f32x4*)(lds + wave*256 + lane*4) = acc;
    __syncthreads();
    if(wave == 0){
      int cl = lane & 15, rb = (lane>>4)*4;
#pragma unroll
      for(int r=0; r<4; r++){
        int m = mt*16 + rb + r, c = nt*16 + cl;
        int idx = lane*4 + r;
        float gir = lds[idx]        + bih[c];
        float giz = lds[256 + idx]  + bih[512 + c];
        float gin = lds[512 + idx]  + bih[1024 + c];
        float ghr = lds[768 + idx]  + bhh[c];
        float ghz = lds[1024 + idx] + bhh[512 + c];
        float ghn = lds[1280 + idx] + bhh[1024 + c];
        if(E){
          const ushort_t* em = E + (size_t)m*1536;
          gir += bf2f(em[c]); giz += bf2f(em[512 + c]); gin += bf2f(em[1024 + c]);
        }
        float rr = sigmoidf_(gir + ghr);
        float zz = sigmoidf_(giz + ghz);
        float nn = fast_tanh(gin + rr*ghn);
        float hp = hprevf[(size_t)m*512 + c];
        float h = (1.f - zz)*nn + zz*hp;
        hf  [(size_t)m*512 + c] = h;
        hdup[(size_t)m*512 + c] = h;
        hswz[swz512(m, c)] = f2bf(h);
      }
    }
  } else {
    if(!do_readout) return;
    int u = blk - 128, mt = u >> 5, nt = u & 31;
    if(wave < 4){
      f32x4 acc = (f32x4){0.f,0.f,0.f,0.f};
      const ushort_t* ap = Amix + ((mt*16 + wave*4)*512) + lane*8;
      const ushort_t* bp = Wrm  + ((nt*16 + wave*4)*512) + lane*8;
#pragma unroll
      for(int kb=0; kb<4; kb++){
        acc = __builtin_amdgcn_mfma_f32_16x16x32_bf16(
            *(const bf16x8*)(ap + kb*512), *(const bf16x8*)(bp + kb*512), acc, 0,0,0);
      }
      *(f32x4*)(lds + wave*256 + lane*4) = acc;
    }
    __syncthreads();
    if(wave == 0){
      int cl = lane & 15, rb = (lane>>4)*4;
#pragma unroll
      for(int r=0; r<4; r++){
        int m = mt*16 + rb + r, c = nt*16 + cl;
        int idx = lane*4 + r;
        float v = lds[idx] + lds[256+idx] + lds[512+idx] + lds[768+idx]
                + br[c] + bf2f(Remb_t[(size_t)m*512 + c]) + R1[(size_t)m*512 + c];
        float o = __shfl_xor(v, 1);
        if(!(cl & 1)) gout[(size_t)m*256 + (c>>1)] = fmaxf(v, o);
      }
    }
  }
}

// ---------------------------------------------------------------- q / tq from h1 (K-split, 4 waves)
__global__ __launch_bounds__(256) void qproj_kernel(const ushort_t* __restrict__ h1swz,
    const ushort_t* __restrict__ qWs, const ushort_t* __restrict__ tqWs,
    float* __restrict__ q, float* __restrict__ tq)
{
  __shared__ float lds[4*256];
  int blk = blockIdx.x;
  int which = blk >> 7, u = blk & 127;
  int mt = u >> 5, nt = u & 31;
  int wave = threadIdx.x >> 6, lane = threadIdx.x & 63;
  const ushort_t* W = which ? tqWs : qWs;
  float* out = which ? tq : q;
  f32x4 acc = (f32x4){0.f,0.f,0.f,0.f};
  const ushort_t* ap = h1swz + ((mt*16 + wave*4)*512) + lane*8;
  const ushort_t* bp = W     + ((nt*16 + wave*4)*512) + lane*8;
#pragma unroll
  for(int kb=0; kb<4; kb++){
    acc = __builtin_amdgcn_mfma_f32_16x16x32_bf16(
        *(const bf16x8*)(ap + kb*512), *(const bf16x8*)(bp + kb*512), acc, 0,0,0);
  }
  *(f32x4*)(lds + wave*256 + lane*4) = acc;
  __syncthreads();
  if(wave == 0){
    int cl = lane & 15, rb = (lane>>4)*4;
#pragma unroll
    for(int r=0; r<4; r++){
      int idx = lane*4 + r;
      out[(size_t)(mt*16 + rb + r)*512 + nt*16 + cl] =
          lds[idx] + lds[256+idx] + lds[512+idx] + lds[768+idx];
    }
  }
}

// ---------------------------------------------------------------- energies + partials (+R1 GEMM blocks)
// grid 704: [0,512) src (b=blk>>3, chunk 50 l), [512,576) topic, [576,704) R1 units.
__global__ __launch_bounds__(256) void energy_partial_kernel(
    const ushort_t* __restrict__ preS, const ushort_t* __restrict__ preT,
    const ushort_t* __restrict__ ctxS, const ushort_t* __restrict__ ctxT,
    const float* __restrict__ q, const float* __restrict__ tq,
    const float* __restrict__ vS, const float* __restrict__ vT,
    const float* __restrict__ maskS, const float* __restrict__ maskT,
    float* __restrict__ eS, float* __restrict__ eT,
    float* __restrict__ partS, float* __restrict__ partT,
    const ushort_t* __restrict__ h1swz, const ushort_t* __restrict__ Wr1s, float* __restrict__ R1)
{
  __shared__ float sh_e[64];
  __shared__ float red[256];
  __shared__ float ldsC[4*512];
  int blk = blockIdx.x, tid = threadIdx.x;
  int wave = tid >> 6, lane = tid & 63;

  if(blk >= 576){
    int u = blk - 576, mt = u >> 5, nt = u & 31;
    f32x4 acc = (f32x4){0.f,0.f,0.f,0.f};
    const ushort_t* ap = h1swz + ((mt*16 + wave*4)*512) + lane*8;
    const ushort_t* bp = Wr1s  + ((nt*16 + wave*4)*512) + lane*8;
#pragma unroll
    for(int kb=0; kb<4; kb++){
      acc = __builtin_amdgcn_mfma_f32_16x16x32_bf16(
          *(const bf16x8*)(ap + kb*512), *(const bf16x8*)(bp + kb*512), acc, 0,0,0);
    }
    *(f32x4*)(ldsC + wave*256 + lane*4) = acc;
    __syncthreads();
    if(wave == 0){
      int cl = lane & 15, rb = (lane>>4)*4;
#pragma unroll
      for(int r=0; r<4; r++){
        int idx = lane*4 + r;
        R1[(size_t)(mt*16 + rb + r)*512 + nt*16 + cl] =
            ldsC[idx] + ldsC[256+idx] + ldsC[512+idx] + ldsC[768+idx];
      }
    }
    return;
  }

  int b, lbase;
  const ushort_t *pre, *ctx; const float *qv, *vv, *mask; float *eout, *part;
  if(blk < 512){
    b = blk >> 3; int ch = blk & 7; lbase = ch*50;
    pre = preS; ctx = ctxS; qv = q + (size_t)b*D_; vv = vS; mask = maskS + (size_t)b*S_;
    eout = eS + (size_t)b*S_;
    part = partS + (size_t)(b*8 + ch)*514;
  } else {
    b = blk - 512; lbase = 0;
    pre = preT; ctx = ctxT; qv = tq + (size_t)b*D_; vv = vT; mask = maskT + (size_t)b*KT_;
    eout = eT + (size_t)b*KT_;
    part = partT + (size_t)b*514;
  }
  float q8[8], v8[8];
  {
    float4 a = *(const float4*)(qv + lane*8);
    float4 c = *(const float4*)(qv + lane*8 + 4);
    q8[0]=a.x;q8[1]=a.y;q8[2]=a.z;q8[3]=a.w;q8[4]=c.x;q8[5]=c.y;q8[6]=c.z;q8[7]=c.w;
    float4 d = *(const float4*)(vv + lane*8);
    float4 e = *(const float4*)(vv + lane*8 + 4);
    v8[0]=d.x;v8[1]=d.y;v8[2]=d.z;v8[3]=d.w;v8[4]=e.x;v8[5]=e.y;v8[6]=e.z;v8[7]=e.w;
  }
  // phase A: energies (4 waves x ~13 l)
  for(int li = wave; li < 50; li += 4){
    int l = lbase + li;
    bf16x8 pk = *(const bf16x8*)(pre + ((size_t)l*B_ + b)*D_ + lane*8);
    float sum = 0.f;
#pragma unroll
    for(int j=0; j<8; j++) sum += v8[j] * fast_tanh(bf2f((ushort_t)pk[j]) + q8[j]);
#pragma unroll
    for(int off=32; off>=1; off>>=1) sum += __shfl_xor(sum, off);
    if(lane == 0){
      float e = (mask[l] > 0.5f) ? -1e6f : sum;
      sh_e[li] = e; eout[l] = e;
    }
  }
  __syncthreads();
  // phase B: chunk softmax stats over 50
  float lm = (tid < 50) ? sh_e[tid] : -3.4e38f;
  red[tid] = lm; __syncthreads();
  for(int s=128; s>0; s>>=1){ if(tid<s) red[tid] = fmaxf(red[tid], red[tid+s]); __syncthreads(); }
  float m = red[0]; __syncthreads();
  if(tid < 50) sh_e[tid] = __expf(sh_e[tid] - m);
  __syncthreads();
  float ls = (tid < 50) ? sh_e[tid] : 0.f;
  red[tid] = ls; __syncthreads();
  for(int s=128; s>0; s>>=1){ if(tid<s) red[tid] += red[tid+s]; __syncthreads(); }
  float ssum = red[0];
  // phase C: weighted ctx partial (4 waves x ~13 l, 16B/lane)
  float c8[8] = {0.f,0.f,0.f,0.f,0.f,0.f,0.f,0.f};
  for(int li = wave; li < 50; li += 4){
    float wl = sh_e[li];
    bf16x8 ck = *(const bf16x8*)(ctx + ((size_t)(lbase+li)*B_ + b)*D_ + lane*8);
#pragma unroll
    for(int j=0; j<8; j++) c8[j] += wl * bf2f((ushort_t)ck[j]);
  }
#pragma unroll
  for(int j=0; j<8; j++) ldsC[wave*512 + lane*8 + j] = c8[j];
  __syncthreads();
  for(int d=tid; d<512; d+=256)
    part[2 + d] = ldsC[d] + ldsC[512+d] + ldsC[1024+d] + ldsC[1536+d];
  if(tid == 0){ part[0] = m; part[1] = ssum; }
}

// ---------------------------------------------------------------- finalize (8 chunks)
__global__ __launch_bounds__(256) void finalize_kernel(
    const float* __restrict__ partS, const float* __restrict__ partT,
    float* __restrict__ eS, float* __restrict__ eT,
    const float* __restrict__ h1, const float* __restrict__ gateW, const float* __restrict__ gateb,
    ushort_t* __restrict__ mixswz, float* __restrict__ mix_out, float* __restrict__ gate_out)
{
  int b = blockIdx.x, tid = threadIdx.x;
  __shared__ float red[256];
  __shared__ float sh[12];  // 0=M 1=St 2=gate 4..11=chunk factors
  float g = 0.f;
  const float* hb = h1 + (size_t)b*D_;
  for(int k=tid; k<D_; k+=256) g += hb[k]*gateW[k];
  red[tid]=g; __syncthreads();
  for(int s=128;s>0;s>>=1){ if(tid<s) red[tid]+=red[tid+s]; __syncthreads(); }
  if(tid==0){
    sh[2] = sigmoidf_(red[0] + gateb[0]);
    const float* p = partS + (size_t)b*8*514;
    float M = -3.4e38f;
    for(int i=0;i<8;i++) M = fmaxf(M, p[i*514]);
    float St = 0.f;
    for(int i=0;i<8;i++){ float f = __expf(p[i*514]-M); sh[4+i]=f; St += p[i*514+1]*f; }
    sh[0]=M; sh[1]=St;
  }
  __syncthreads();
  float M = sh[0], gate = sh[2];
  float rSt = __fdividef(1.f, sh[1]);
  float* er = eS + (size_t)b*S_;
  for(int l=tid; l<S_; l+=256) er[l] = __expf(er[l]-M)*rSt;
  const float* pT = partT + (size_t)b*514;
  float Mt = pT[0];
  float rStt = __fdividef(1.f, pT[1]);
  float* etr = eT + (size_t)b*KT_;
  for(int l=tid; l<KT_; l+=256) etr[l] = __expf(etr[l]-Mt)*rStt;
  const float* p = partS + (size_t)b*8*514;
  for(int d=tid; d<D_; d+=256){
    float c = 0.f;
#pragma unroll
    for(int i=0;i<8;i++) c += p[i*514 + 2 + d]*sh[4+i];
    c *= rSt;
    float tc = pT[2+d]*rStt;
    float mx = gate*c + (1.f-gate)*tc;
    mixswz[swz512(b, d)] = f2bf(mx);
    mix_out[(size_t)b*D_+d] = mx;
  }
  if(tid==0) gate_out[b] = gate;
}

// ================================================================ host
extern "C" void kernel_launch(void* const* d_in, const int* in_sizes, int n_in,
                              void* d_out, int out_size, void* d_ws, size_t ws_size,
                              hipStream_t stream){
  const int*   tgt      = (const int*)  d_in[0];
  const float* hidden   = (const float*)d_in[1];
  const float* context  = (const float*)d_in[2];
  const float* smask    = (const float*)d_in[3];
  const float* tctx_in  = (const float*)d_in[4];
  const float* tmask    = (const float*)d_in[5];
  const float* mix_init = (const float*)d_in[6];
  const float* emb      = (const float*)d_in[7];
  const float* Wih0     = (const float*)d_in[8];
  const float* Whh0     = (const float*)d_in[9];
  const float* bih0     = (const float*)d_in[10];
  const float* bhh0     = (const float*)d_in[11];
  const float* Wih1     = (const float*)d_in[12];
  const float* Whh1     = (const float*)d_in[13];
  const float* bih1     = (const float*)d_in[14];
  const float* bhh1     = (const float*)d_in[15];
  const float* preW     = (const float*)d_in[16];
  const float* preB     = (const float*)d_in[17];
  const float* qW       = (const float*)d_in[18];
  const float* vS       = (const float*)d_in[19];
  const float* tpreW    = (const float*)d_in[20];
  const float* tpreB    = (const float*)d_in[21];
  const float* tqW      = (const float*)d_in[22];
  const float* vT       = (const float*)d_in[23];
  const float* Wr       = (const float*)d_in[24];
  const float* br       = (const float*)d_in[25];
  const float* gW       = (const float*)d_in[26];
  const float* gB       = (const float*)d_in[27];

  float* out = (float*)d_out;
  const size_t o0=0, o1=819200, o2=884736, o3=2164736, o4=2324736, o5=2357504;

  unsigned char* p = (unsigned char*)d_ws;
  auto carve = [&](size_t bytes)->void*{
    void* r = (void*)p; p += (bytes + 255) & ~(size_t)255; return r;
  };
  ushort_t* ctxb   = (ushort_t*)carve((size_t)S_*B_*D_*2);
  ushort_t* tctxb  = (ushort_t*)carve((size_t)KT_*B_*D_*2);
  ushort_t* preb   = (ushort_t*)carve((size_t)S_*B_*D_*2);
  ushort_t* tpreb  = (ushort_t*)carve((size_t)KT_*B_*D_*2);
  ushort_t* preWb  = (ushort_t*)carve((size_t)D_*D_*2);
  ushort_t* tpreWb = (ushort_t*)carve((size_t)D_*D_*2);
  ushort_t* Wih0b  = (ushort_t*)carve((size_t)1536*1024*2);   // plain, for E0 gemm
  ushort_t* Wrb    = (ushort_t*)carve((size_t)512*1536*2);    // plain, for Remb gemm
  ushort_t* Aembb  = (ushort_t*)carve((size_t)T_*B_*D_*2);
  ushort_t* E0     = (ushort_t*)carve((size_t)T_*B_*1536*2);
  ushort_t* Remb   = (ushort_t*)carve((size_t)T_*B_*512*2);
  // swizzled weights (each 512x512 bf16 = 512KB)
  ushort_t* Wg0s = (ushort_t*)carve((size_t)3*512*512*2);
  ushort_t* Wh0s = (ushort_t*)carve((size_t)3*512*512*2);
  ushort_t* Wg1s = (ushort_t*)carve((size_t)3*512*512*2);
  ushort_t* Wh1s = (ushort_t*)carve((size_t)3*512*512*2);
  ushort_t* qWs  = (ushort_t*)carve((size_t)512*512*2);
  ushort_t* tqWs = (ushort_t*)carve((size_t)512*512*2);
  ushort_t* Wr1s = (ushort_t*)carve((size_t)512*512*2);
  ushort_t* Wrms = (ushort_t*)carve((size_t)512*512*2);
  // states
  float* h0f0 = (float*)carve((size_t)B_*D_*4);
  float* h0f1 = (float*)carve((size_t)B_*D_*4);
  float* h1f0 = (float*)carve((size_t)B_*D_*4);
  float* h1f1 = (float*)carve((size_t)B_*D_*4);
  ushort_t* h0s0 = (ushort_t*)carve((size_t)B_*D_*2);
  ushort_t* h0s1 = (ushort_t*)carve((size_t)B_*D_*2);
  ushort_t* h1s0 = (ushort_t*)carve((size_t)B_*D_*2);
  ushort_t* h1s1 = (ushort_t*)carve((size_t)B_*D_*2);
  ushort_t* mixswz = (ushort_t*)carve((size_t)B_*D_*2);
  float* qws  = (float*)carve((size_t)B_*D_*4);
  float* tqws = (float*)carve((size_t)B_*D_*4);
  float* R1   = (float*)carve((size_t)B_*D_*4);
  float* partS= (float*)carve((size_t)B_*8*514*4);
  float* partT= (float*)carve((size_t)B_*514*4);

  // -------- one-time precompute --------
  {
    auto cv = [&](const float* src, ushort_t* dst, int n){
      f32_to_bf16_kernel<<<(n+255)/256,256,0,stream>>>(src, dst, n);
    };
    cv(context, ctxb, S_*B_*D_);
    cv(tctx_in, tctxb, KT_*B_*D_);
    cv(preW, preWb, D_*D_);
    cv(tpreW, tpreWb, D_*D_);
    cv(Wih0, Wih0b, 1536*1024);
    cv(Wr, Wrb, 512*1536);
    auto sw = [&](const float* W, ushort_t* dst, int row0, int col0, int stride){
      swizzle_w_kernel<<<1024,256,0,stream>>>(W, dst, row0, col0, stride);
    };
    for(int g=0; g<3; g++){
      sw(Wih0, Wg0s + g*262144, g*512, 512, 1024);
      sw(Whh0, Wh0s + g*262144, g*512, 0, 512);
      sw(Wih1, Wg1s + g*262144, g*512, 0, 512);
      sw(Whh1, Wh1s + g*262144, g*512, 0, 512);
    }
    sw(qW,  qWs,  0, 0, 512);
    sw(tqW, tqWs, 0, 0, 512);
    sw(Wr,  Wr1s, 0, 512, 1536);
    sw(Wr,  Wrms, 0, 1024, 1536);
    gather_emb_kernel<<<T_*B_,256,0,stream>>>(tgt, emb, Aembb);
    init_state_kernel<<<(B_*D_+255)/256,256,0,stream>>>(hidden, mix_init, h0f1, h0s1, h1f1, h1s1, mixswz);
    pre_gemm_kernel<<<(S_*B_)/64,256,0,stream>>>(ctxb,  preWb,  preB,  preb);
    pre_gemm_kernel<<<(KT_*B_)/64,256,0,stream>>>(tctxb, tpreWb, tpreB, tpreb);
    gemm_nb_kernel<<<dim3(T_*B_/64,3),256,0,stream>>>(Aembb, Wih0b, E0, 1024, 0, 1536);
    gemm_nb_kernel<<<dim3(T_*B_/64,1),256,0,stream>>>(Aembb, Wrb, Remb, 1536, 0, 512);
  }

  float* h0f[2] = {h0f0, h0f1};
  float* h1f[2] = {h1f0, h1f1};
  ushort_t* h0s[2] = {h0s0, h0s1};
  ushort_t* h1s[2] = {h1s0, h1s1};

  for(int t=0; t<T_; t++){
    int cur = t & 1, prv = (t+1) & 1;
    int tprev = (t>0) ? t-1 : 0;
    // K1: GRU0 + readout(t-1)
    gru_step_kernel<<<256,384,0,stream>>>(
        1, (t>0)?1:0,
        mixswz, h0s[prv], Wg0s, Wh0s,
        E0 + (size_t)t*B_*1536, bih0, bhh0,
        h0f[prv], h0f[cur], h0s[cur], out + o1,
        mixswz, Wrms, Remb + (size_t)tprev*B_*512, R1, br,
        out + o0 + (size_t)tprev*B_*256);
    // K2: GRU1
    gru_step_kernel<<<128,384,0,stream>>>(
        1, 0,
        h0s[cur], h1s[prv], Wg1s, Wh1s,
        (const ushort_t*)nullptr, bih1, bhh1,
        h1f[prv], h1f[cur], h1s[cur], out + o1 + B_*D_,
        mixswz, Wrms, Remb, R1, br, out + o0);
    // K3: q, tq
    qproj_kernel<<<256,256,0,stream>>>(h1s[cur], qWs, tqWs, qws, tqws);
    // K4: energies + partials + R1
    energy_partial_kernel<<<704,256,0,stream>>>(preb, tpreb, ctxb, tctxb, qws, tqws, vS, vT,
        smask, tmask,
        out + o2 + (size_t)t*B_*S_, out + o3 + (size_t)t*B_*KT_, partS, partT,
        h1s[cur], Wr1s, R1);
    // K5: finalize
    finalize_kernel<<<64,256,0,stream>>>(partS, partT,
        out + o2 + (size_t)t*B_*S_, out + o3 + (size_t)t*B_*KT_,
        h1f[cur], gW, gB, mixswz, out + o4, out + o5 + (size_t)t*B_);
  }
  // tail: readout for step T-1
  gru_step_kernel<<<256,384,0,stream>>>(
      0, 1,
      mixswz, h0s1, Wg0s, Wh0s,
      (const ushort_t*)nullptr, bih0, bhh0,
      h0f1, h0f0, h0s0, out + o1,
      mixswz, Wrms, Remb + (size_t)(T_-1)*B_*512, R1, br,
      out + o0 + (size_t)(T_-1)*B_*256);
}